// Round 16
// baseline (3036.850 us; speedup 1.0000x reference)
//
#include <hip/hip_runtime.h>
#include <cstdint>

#define V_SIZE 50257
#define V_PAD  50432            // 197 * 256
#define NCB    197              // logits col-blocks
#define D_DIM  1024
#define H_NUM  16
#define L_NUM  8
#define T_LEN  1024
#define B_NUM  4
#define HD_DIM 64
#define M_ROWS 4096
#define LN_EPS 1e-5f

typedef __attribute__((ext_vector_type(8))) __bf16 bf16x8;
typedef __attribute__((ext_vector_type(4))) float f32x4;
typedef __attribute__((ext_vector_type(4))) float fv4;
typedef __attribute__((ext_vector_type(8))) unsigned short u16x8;

__device__ __forceinline__ unsigned short f2bf(float f) {
  unsigned u = __builtin_bit_cast(unsigned, f);
  u += 0x7fffu + ((u >> 16) & 1u);   // RNE
  return (unsigned short)(u >> 16);
}

__device__ __forceinline__ void gload_lds16(const void* g, void* l) {
  typedef const __attribute__((address_space(1))) unsigned int* gp_t;
  typedef __attribute__((address_space(3))) unsigned int* lp_t;
  __builtin_amdgcn_global_load_lds((gp_t)g, (lp_t)l, 16, 0, 0);
}

__device__ __forceinline__ f32x4 mfma16(bf16x8 a, bf16x8 b, f32x4 c) {
  return __builtin_amdgcn_mfma_f32_16x16x32_bf16(a, b, c, 0, 0, 0);
}

#define BARSB() { __builtin_amdgcn_s_barrier(); __builtin_amdgcn_sched_barrier(0); }
#define SCHB()  __builtin_amdgcn_sched_barrier(0)

// ---------------- embedding ----------------
__global__ __launch_bounds__(256) void embed_kernel(const int* __restrict__ ctx,
                                                    const float* __restrict__ wte,
                                                    const float* __restrict__ wpe,
                                                    float* __restrict__ x) {
  int i = blockIdx.x * blockDim.x + threadIdx.x;
  if (i >= M_ROWS * D_DIM) return;
  int bt = i / D_DIM, d = i - bt * D_DIM;
  int t = bt & (T_LEN - 1);
  x[i] = wte[(size_t)ctx[bt] * D_DIM + d] + wpe[(size_t)t * D_DIM + d];
}

// ---------------- fp32 -> bf16 weight conversion (NT source loads) ----------------
__global__ __launch_bounds__(256) void conv_layer_kernel(const float* __restrict__ wa,
                                                         const float* __restrict__ wp,
                                                         const float* __restrict__ wf,
                                                         const float* __restrict__ wo,
                                                         unsigned short* __restrict__ oa,
                                                         unsigned short* __restrict__ op,
                                                         unsigned short* __restrict__ of,
                                                         unsigned short* __restrict__ oo) {
  long i = (long)(blockIdx.x * 256 + threadIdx.x) * 8;
  const float* src; unsigned short* dst; long off;
  if (i < 3145728L)      { src = wa; dst = oa; off = i; }
  else if (i < 4194304L) { src = wp; dst = op; off = i - 3145728L; }
  else if (i < 8388608L) { src = wf; dst = of; off = i - 4194304L; }
  else                   { src = wo; dst = oo; off = i - 8388608L; }
  fv4 v0 = __builtin_nontemporal_load((const fv4*)(src + off));
  fv4 v1 = __builtin_nontemporal_load((const fv4*)(src + off + 4));
  u16x8 o;
  o[0] = f2bf(v0[0]); o[1] = f2bf(v0[1]); o[2] = f2bf(v0[2]); o[3] = f2bf(v0[3]);
  o[4] = f2bf(v1[0]); o[5] = f2bf(v1[1]); o[6] = f2bf(v1[2]); o[7] = f2bf(v1[3]);
  *(u16x8*)(dst + off) = o;
}

__global__ __launch_bounds__(256) void conv_kernel(const float* __restrict__ in,
                                                   unsigned short* __restrict__ out, long n) {
  long i = (long)(blockIdx.x * 256 + threadIdx.x) * 8;
  if (i >= n) return;
  fv4 v0 = __builtin_nontemporal_load((const fv4*)(in + i));
  fv4 v1 = __builtin_nontemporal_load((const fv4*)(in + i + 4));
  u16x8 o;
  o[0] = f2bf(v0[0]); o[1] = f2bf(v0[1]); o[2] = f2bf(v0[2]); o[3] = f2bf(v0[3]);
  o[4] = f2bf(v1[0]); o[5] = f2bf(v1[1]); o[6] = f2bf(v1[2]); o[7] = f2bf(v1[3]);
  *(u16x8*)(out + i) = o;
}

// ---------------- layernorm: fp32 in -> bf16 out ----------------
__global__ __launch_bounds__(256) void layernorm_kernel(const float* __restrict__ x,
                                                        const float* __restrict__ g,
                                                        const float* __restrict__ b,
                                                        unsigned short* __restrict__ o) {
  int r = blockIdx.x;
  int tid = threadIdx.x;
  const float* row = x + (size_t)r * D_DIM;
  float4 v = *(const float4*)(row + tid * 4);
  float s  = v.x + v.y + v.z + v.w;
  float s2 = v.x * v.x + v.y * v.y + v.z * v.z + v.w * v.w;
  #pragma unroll
  for (int off = 32; off; off >>= 1) {
    s  += __shfl_xor(s, off);
    s2 += __shfl_xor(s2, off);
  }
  __shared__ float a1[4], a2[4];
  int w = tid >> 6, lane = tid & 63;
  if (lane == 0) { a1[w] = s; a2[w] = s2; }
  __syncthreads();
  s  = a1[0] + a1[1] + a1[2] + a1[3];
  s2 = a2[0] + a2[1] + a2[2] + a2[3];
  float mu  = s * (1.0f / D_DIM);
  float var = s2 * (1.0f / D_DIM) - mu * mu;
  float rs  = rsqrtf(var + LN_EPS);
  int d = tid * 4;
  float4 gv = *(const float4*)(g + d);
  float4 bv = *(const float4*)(b + d);
  ushort4 ov;
  ov.x = f2bf((v.x - mu) * rs * gv.x + bv.x);
  ov.y = f2bf((v.y - mu) * rs * gv.y + bv.y);
  ov.z = f2bf((v.z - mu) * rs * gv.z + bv.z);
  ov.w = f2bf((v.w - mu) * rs * gv.w + bv.w);
  *(ushort4*)(o + (size_t)r * D_DIM + d) = ov;
}

// ---------------- m97-structure 128x128 bf16 MFMA GEMM (proj/out) ----------
template<int EPI>
__global__ __launch_bounds__(256) void mfma_gemm(const unsigned short* __restrict__ A,
                                                 const unsigned short* __restrict__ W,
                                                 const float* R, void* Cout,
                                                 int K, int ldc, int nreal) {
  __shared__ unsigned short As[128 * 32];
  __shared__ unsigned short Bs[128 * 32];
  const int tid  = threadIdx.x;
  const int wave = tid >> 6, lane = tid & 63;
  const int wr = wave >> 1, wc = wave & 1;
  const long row0 = (long)blockIdx.y * 128;
  const long col0 = (long)blockIdx.x * 128;
  f32x4 acc[4][4] = {};
  const int frow = lane & 15;
  const int fk   = (lane >> 4) * 8;
  const int b0 = wave * 2048 + lane * 16;
  for (int k0 = 0; k0 < K; k0 += 32) {
    #pragma unroll
    for (int c = 0; c < 2; ++c) {
      int b = b0 + c * 1024;
      int r = b >> 6, ke = (b & 63) >> 1;
      gload_lds16(A + (row0 + r) * (long)K + k0 + ke, (char*)As + b);
      gload_lds16(W + (col0 + r) * (long)K + k0 + ke, (char*)Bs + b);
    }
    __syncthreads();
    bf16x8 af[4], bfr[4];
    #pragma unroll
    for (int i = 0; i < 4; ++i)
      af[i] = *(const bf16x8*)(As + (wr * 64 + i * 16 + frow) * 32 + fk);
    #pragma unroll
    for (int j = 0; j < 4; ++j)
      bfr[j] = *(const bf16x8*)(Bs + (wc * 64 + j * 16 + frow) * 32 + fk);
    #pragma unroll
    for (int i = 0; i < 4; ++i)
      #pragma unroll
      for (int j = 0; j < 4; ++j)
        acc[i][j] = mfma16(af[i], bfr[j], acc[i][j]);
    __syncthreads();
  }
  const int crow = (lane >> 4) * 4;
  const int ccol = lane & 15;
  #pragma unroll
  for (int i = 0; i < 4; ++i) {
    #pragma unroll
    for (int r = 0; r < 4; ++r) {
      long row = row0 + wr * 64 + i * 16 + crow + r;
      #pragma unroll
      for (int j = 0; j < 4; ++j) {
        long col = col0 + wc * 64 + j * 16 + ccol;
        float v = acc[i][j][r];
        if (EPI == 1) {
          ((float*)Cout)[row * (long)ldc + col] = v + R[row * (long)ldc + col];
        } else {
          ((float*)Cout)[row * (long)ldc + col] = v;
        }
      }
    }
  }
}

// ---------------- 256x256 software-pipelined bf16 GEMM, 16x16x32 MFMA ----------
__device__ __forceinline__ void stage_chunk8(const unsigned short* __restrict__ base,
                                             long rbase, int K, long gk,
                                             char* cb, int tid) {
  #pragma unroll
  for (int j = 0; j < 2; ++j) {
    int db = j * 8192 + tid * 16;
    int lb = db ^ (((db >> 7) & 3) << 4);
    long r = lb >> 6;
    int e = (lb & 63) >> 1;
    gload_lds16(base + (rbase + r) * (long)K + gk + e, cb + db);
  }
}

__device__ __forceinline__ bf16x8 rdfrag(const char* cb, int rr, int lhi) {
  int p = (rr << 6) + (lhi << 4);
  p ^= ((rr >> 1) & 3) << 4;
  return *(const bf16x8*)(cb + p);
}

template<int EPI>
__global__ __launch_bounds__(512, 1) void gemm8p(const unsigned short* __restrict__ A,
                                                 const unsigned short* __restrict__ W,
                                                 void* Cout, int K, int ldc, int nreal,
                                                 int nbx, int xcd,
                                                 float* __restrict__ psum) {
  __shared__ char lds[131072];
  const int tid  = threadIdx.x;
  const int lane = tid & 63;
  const int wave = tid >> 6;
  const int wr = wave >> 2, wc = wave & 3;
  const int lhi = lane >> 4, llo = lane & 15;
  int bid = blockIdx.x;
  if (xcd) { int per = (int)gridDim.x >> 3; bid = (bid & 7) * per + (bid >> 3); }
  const int brow = bid % nbx;
  const int bcol = bid / nbx;
  const long row0 = (long)brow * 256;
  const long col0 = (long)bcol * 256;
  char* Ab0 = (char*)lds;
  char* Bb0 = (char*)lds + 65536;
  const int nt = K >> 6;   // nt >= 3 assumed (all uses: nt = 16)

  stage_chunk8(W, col0, K, 0,  Bb0,         tid);
  stage_chunk8(A, row0, K, 0,  Ab0,         tid);
  stage_chunk8(W, col0, K, 32, Bb0 + 16384, tid);
  stage_chunk8(A, row0, K, 32, Ab0 + 16384, tid);
  stage_chunk8(W, col0, K, 64, Bb0 + 32768, tid);
  stage_chunk8(A, row0, K, 64, Ab0 + 32768, tid);
  stage_chunk8(W, col0, K, 96, Bb0 + 49152, tid);
  asm volatile("s_waitcnt vmcnt(10)" ::: "memory");
  BARSB();

  const int arow  = wr * 128 + llo;
  const int brow_ = wc * 64 + llo;

  bf16x8 aa0[4], aa1[4], bb0[4], bb1[4];
  #pragma unroll
  for (int m = 0; m < 4; ++m) aa0[m] = rdfrag(Ab0, arow + m * 16, lhi);
  #pragma unroll
  for (int n = 0; n < 4; ++n) bb0[n] = rdfrag(Bb0, brow_ + n * 16, lhi);

  f32x4 acc[8][4] = {};
  for (int t = 0; t < nt; ++t) {
    char* Ac = Ab0 + (t & 1) * 32768;
    char* Bc = Bb0 + (t & 1) * 32768;
    char* An = Ab0 + ((t + 1) & 1) * 32768;
    char* Bn = Bb0 + ((t + 1) & 1) * 32768;
    // ===== S0
    #pragma unroll
    for (int m = 0; m < 4; ++m) aa1[m] = rdfrag(Ac, arow + 64 + m * 16, lhi);
    asm volatile("s_waitcnt lgkmcnt(4)" ::: "memory");
    SCHB();
    if (t + 1 < nt) stage_chunk8(A, row0, K, (long)(t + 1) * 64 + 32, An + 16384, tid);
    __builtin_amdgcn_s_setprio(1);
    #pragma unroll
    for (int m = 0; m < 4; ++m)
      #pragma unroll
      for (int n = 0; n < 4; ++n)
        acc[m][n] = mfma16(aa0[m], bb0[n], acc[m][n]);
    __builtin_amdgcn_s_setprio(0);
    SCHB();
    if (t < nt - 1) { asm volatile("s_waitcnt vmcnt(8)" ::: "memory"); }
    else            { asm volatile("s_waitcnt vmcnt(0)" ::: "memory"); }
    BARSB();
    // ===== S1
    #pragma unroll
    for (int m = 0; m < 4; ++m) aa0[m] = rdfrag(Ac + 16384, arow + m * 16, lhi);
    #pragma unroll
    for (int n = 0; n < 4; ++n) bb1[n] = rdfrag(Bc + 16384, brow_ + n * 16, lhi);
    asm volatile("s_waitcnt lgkmcnt(8)" ::: "memory");
    SCHB();
    if (t + 2 < nt) stage_chunk8(W, col0, K, (long)(t + 2) * 64, Bc, tid);
    __builtin_amdgcn_s_setprio(1);
    #pragma unroll
    for (int m = 0; m < 4; ++m)
      #pragma unroll
      for (int n = 0; n < 4; ++n)
        acc[m + 4][n] = mfma16(aa1[m], bb0[n], acc[m + 4][n]);
    __builtin_amdgcn_s_setprio(0);
    SCHB();
    BARSB();
    // ===== S2
    #pragma unroll
    for (int m = 0; m < 4; ++m) aa1[m] = rdfrag(Ac + 16384, arow + 64 + m * 16, lhi);
    asm volatile("s_waitcnt lgkmcnt(4)" ::: "memory");
    SCHB();
    if (t + 2 < nt) stage_chunk8(A, row0, K, (long)(t + 2) * 64, Ac, tid);
    __builtin_amdgcn_s_setprio(1);
    #pragma unroll
    for (int m = 0; m < 4; ++m)
      #pragma unroll
      for (int n = 0; n < 4; ++n)
        acc[m][n] = mfma16(aa0[m], bb1[n], acc[m][n]);
    __builtin_amdgcn_s_setprio(0);
    SCHB();
    if (t <= nt - 3)      { asm volatile("s_waitcnt vmcnt(8)" ::: "memory"); }
    else if (t == nt - 2) { asm volatile("s_waitcnt vmcnt(4)" ::: "memory"); }
    else                  { asm volatile("s_waitcnt vmcnt(0)" ::: "memory"); }
    BARSB();
    // ===== S3
    if (t + 1 < nt) {
      #pragma unroll
      for (int m = 0; m < 4; ++m) aa0[m] = rdfrag(An, arow + m * 16, lhi);
      #pragma unroll
      for (int n = 0; n < 4; ++n) bb0[n] = rdfrag(Bn, brow_ + n * 16, lhi);
      asm volatile("s_waitcnt lgkmcnt(8)" ::: "memory");
    } else {
      asm volatile("s_waitcnt lgkmcnt(0)" ::: "memory");
    }
    SCHB();
    if (t + 2 < nt) stage_chunk8(W, col0, K, (long)(t + 2) * 64 + 32, Bc + 16384, tid);
    __builtin_amdgcn_s_setprio(1);
    #pragma unroll
    for (int m = 0; m < 4; ++m)
      #pragma unroll
      for (int n = 0; n < 4; ++n)
        acc[m + 4][n] = mfma16(aa1[m], bb1[n], acc[m + 4][n]);
    __builtin_amdgcn_s_setprio(0);
    SCHB();
    BARSB();
  }

  // ---- epilogue: stores (C/D 16x16 layout: col=lane&15, row=(lane>>4)*4+reg)
  #pragma unroll
  for (int mi = 0; mi < 8; ++mi) {
    #pragma unroll
    for (int rg = 0; rg < 4; ++rg) {
      long row = row0 + wr * 128 + mi * 16 + lhi * 4 + rg;
      #pragma unroll
      for (int n = 0; n < 4; ++n) {
        long col = col0 + wc * 64 + n * 16 + llo;
        float v = acc[mi][n][rg];
        if (EPI == 0) {
          if (col < nreal) ((float*)Cout)[row * (long)ldc + col] = v;
        } else if (EPI == 2) {
          float gl = 0.5f * v * (1.0f + erff(v * 0.70710678118654752440f));
          ((unsigned short*)Cout)[row * (long)ldc + col] = f2bf(gl);
        } else {
          ((unsigned short*)Cout)[row * (long)ldc + col] = f2bf(v);
        }
      }
    }
  }

  if (EPI == 0) {
    // exp-direct LSE partials (logits are small; no max tracking needed)
    float* red = (float*)lds;   // [256 rows][4 wc]
    #pragma unroll
    for (int mi = 0; mi < 8; ++mi) {
      #pragma unroll
      for (int rg = 0; rg < 4; ++rg) {
        float e = 0.f;
        #pragma unroll
        for (int n = 0; n < 4; ++n) {
          long col = col0 + wc * 64 + n * 16 + llo;
          if (col < nreal) e += __expf(acc[mi][n][rg]);
        }
        #pragma unroll
        for (int off = 1; off < 16; off <<= 1) e += __shfl_xor(e, off);
        if (llo == 0) {
          int rl = wr * 128 + mi * 16 + lhi * 4 + rg;
          red[rl * 4 + wc] = e;
        }
      }
    }
    __syncthreads();
    if (tid < 256) {
      float s = red[tid * 4 + 0] + red[tid * 4 + 1] + red[tid * 4 + 2] + red[tid * 4 + 3];
      psum[(long)bcol * M_ROWS + row0 + tid] = s;
    }
  }
}

// ---------------- MFMA flash attention: swapped QK^T + K/V LDS double-buffer --------
// One barrier per KV-tile: tile st+1's staged regs write LDS[(st+1)&1] while
// other waves may still compute tile st from LDS[st&1]; buffer (st+1)&1 was
// last read at tile st-1, and every wave's arrival at sync(st) follows its
// compute(st-1) -> WAR-safe with a single sync at the top of each tile.
__global__ __launch_bounds__(512) void flash_attn_kernel(const unsigned short* __restrict__ qkv,
                                                         unsigned short* __restrict__ y) {
  __shared__ unsigned short Kls[2][64 * 64];
  __shared__ unsigned short Vtls[2][64 * 64];
  __shared__ unsigned short Pls[8][16 * 64];
  const int tid = threadIdx.x, wave = tid >> 6, lane = tid & 63;
  const int qt = blockIdx.x;                     // 0..7
  const int h = blockIdx.y & (H_NUM - 1), b = blockIdx.y >> 4;
  const int q0 = qt * 128;
  const int lhi = lane >> 4, llo = lane & 15;

  const int qrow = q0 + wave * 16 + llo;
  const unsigned short* qptr =
      qkv + ((size_t)(b * T_LEN + qrow)) * 3072 + h * HD_DIM + lhi * 8;
  const bf16x8 qa0 = *(const bf16x8*)qptr;
  const bf16x8 qa1 = *(const bf16x8*)(qptr + 32);

  f32x4 o[4] = {};
  float m = -1e30f, l = 0.f;      // per-lane running stats for q = llo

  const unsigned short* kg = qkv + (size_t)b * T_LEN * 3072 + D_DIM + h * HD_DIM;
  const unsigned short* vg = kg + D_DIM;

  const int vs0 = ((tid & 255) >> 3) * 2, vd0 = (tid & 7) * 8;   // tid<256: V
  const int t2 = tid - 256;
  const int krow = (t2 & 255) >> 2, kcol = (t2 & 3) * 16;        // tid>=256: K

  const int ntiles = 2 * qt + 2;

  // preload tile 0 into registers
  u16x8 ra, rc;
  if (tid < 256) {
    const unsigned short* src = vg + (size_t)vs0 * 3072 + vd0;
    ra = *(const u16x8*)src;
    rc = *(const u16x8*)(src + 3072);
  } else {
    const unsigned short* src = kg + (size_t)krow * 3072 + kcol;
    ra = *(const u16x8*)src;
    rc = *(const u16x8*)(src + 8);
  }

  for (int st = 0; st < ntiles; ++st) {
    char* Kb = (char*)Kls[st & 1];
    char* Vb = (char*)Vtls[st & 1];
    // ---- write staged regs -> LDS[st&1] (swizzled) ----
    if (tid < 256) {
      #pragma unroll
      for (int j = 0; j < 8; ++j) {
        int d = vd0 + j;
        unsigned val = (unsigned)ra[j] | ((unsigned)rc[j] << 16);
        *(unsigned*)(Vb + ((d * 128 + vs0 * 2) ^ ((d & 7) << 4))) = val;
      }
    } else {
      int base = krow * 128 + kcol * 2;
      int sw = (krow & 7) << 4;
      *(u16x8*)(Kb + ((base) ^ sw))      = ra;
      *(u16x8*)(Kb + ((base + 16) ^ sw)) = rc;
    }
    __syncthreads();   // LDS[st&1] ready; all waves done with tile st-1
    // ---- issue next tile's global loads (hidden under compute) ----
    if (st + 1 < ntiles) {
      const int s1 = (st + 1) * 64;
      if (tid < 256) {
        const unsigned short* src = vg + (size_t)(s1 + vs0) * 3072 + vd0;
        ra = *(const u16x8*)src;
        rc = *(const u16x8*)(src + 3072);
      } else {
        const unsigned short* src = kg + (size_t)(s1 + krow) * 3072 + kcol;
        ra = *(const u16x8*)src;
        rc = *(const u16x8*)(src + 8);
      }
    }

    const int s0 = st * 64;
    // ---- swapped QK^T: D = K_tile(A) x Q(B) -> S^T[key][q], col=q=llo ----
    f32x4 t_acc[4] = {};
    #pragma unroll
    for (int kt = 0; kt < 4; ++kt) {
      int kr = kt * 16 + llo;
      int sw = (kr & 7) << 4;
      bf16x8 kb0 = *(const bf16x8*)(Kb + ((kr * 128 + lhi * 16) ^ sw));
      bf16x8 kb1 = *(const bf16x8*)(Kb + ((kr * 128 + 64 + lhi * 16) ^ sw));
      t_acc[kt] = mfma16(kb0, qa0, t_acc[kt]);
      t_acc[kt] = mfma16(kb1, qa1, t_acc[kt]);
    }

    // ---- softmax: lane owns q = q0+wave*16+llo; 16 scores in registers ----
    const int qg = q0 + wave * 16 + llo;
    float p[4][4];
    float tmax = -1e30f;
    #pragma unroll
    for (int kt = 0; kt < 4; ++kt) {
      #pragma unroll
      for (int rg = 0; rg < 4; ++rg) {
        int key = s0 + kt * 16 + lhi * 4 + rg;
        float sv = (key <= qg) ? t_acc[kt][rg] * 0.125f : -1e30f;
        p[kt][rg] = sv;
        tmax = fmaxf(tmax, sv);
      }
    }
    tmax = fmaxf(tmax, __shfl_xor(tmax, 16));
    tmax = fmaxf(tmax, __shfl_xor(tmax, 32));
    float mn = fmaxf(m, tmax);
    float corr = __expf(m - mn);
    m = mn;
    float ps = 0.f;
    #pragma unroll
    for (int kt = 0; kt < 4; ++kt) {
      #pragma unroll
      for (int rg = 0; rg < 4; ++rg) {
        p[kt][rg] = __expf(p[kt][rg] - mn);
        ps += p[kt][rg];
      }
    }
    ps += __shfl_xor(ps, 16);
    ps += __shfl_xor(ps, 32);
    l = l * corr + ps;
    // redistribute corr to o's rows (q' = lhi*4 + r held by lane llo=q')
    float corr4[4];
    #pragma unroll
    for (int r = 0; r < 4; ++r) corr4[r] = __shfl(corr, lhi * 4 + r);
    #pragma unroll
    for (int dt = 0; dt < 4; ++dt)
      #pragma unroll
      for (int r = 0; r < 4; ++r) o[dt][r] *= corr4[r];

    // ---- write P (bf16) to wave-private LDS [q=llo][k], swizzled ----
    unsigned short* pw = Pls[wave];
    {
      int sw = (llo & 7) << 4;
      #pragma unroll
      for (int kt = 0; kt < 4; ++kt) {
        #pragma unroll
        for (int rg = 0; rg < 4; ++rg) {
          int k = kt * 16 + lhi * 4 + rg;
          *(unsigned short*)((char*)pw + ((llo * 128 + k * 2) ^ sw)) = f2bf(p[kt][rg]);
        }
      }
    }
    asm volatile("s_waitcnt lgkmcnt(0)" ::: "memory");

    int psw = (llo & 7) << 4;
    bf16x8 pa0 = *(const bf16x8*)((char*)pw + ((llo * 128 + lhi * 16) ^ psw));
    bf16x8 pa1 = *(const bf16x8*)((char*)pw + ((llo * 128 + 64 + lhi * 16) ^ psw));
    #pragma unroll
    for (int dt = 0; dt < 4; ++dt) {
      int vr = dt * 16 + llo;
      int sw = (vr & 7) << 4;
      bf16x8 vb0 = *(const bf16x8*)(Vb + ((vr * 128 + lhi * 16) ^ sw));
      bf16x8 vb1 = *(const bf16x8*)(Vb + ((vr * 128 + 64 + lhi * 16) ^ sw));
      o[dt] = mfma16(pa0, vb0, o[dt]);
      o[dt] = mfma16(pa1, vb1, o[dt]);
    }
    // no end-of-tile barrier (double-buffered K/V)
  }

  // ---- epilogue: l for o's rows fetched from lane llo = lhi*4+r ----
  #pragma unroll
  for (int r = 0; r < 4; ++r) {
    float lr = __shfl(l, lhi * 4 + r);
    float inv = 1.0f / lr;
    long row = q0 + wave * 16 + lhi * 4 + r;
    #pragma unroll
    for (int dt = 0; dt < 4; ++dt) {
      long col = h * HD_DIM + dt * 16 + llo;
      y[(row + (size_t)b * T_LEN) * D_DIM + col] = f2bf(o[dt][r] * inv);
    }
  }
}

// ---------------- loss: sum per-colblock exp-partials ----------------
__global__ __launch_bounds__(256) void loss_combine_kernel(const float* __restrict__ psum,
                                                           const float* __restrict__ logits,
                                                           const int* __restrict__ tgt,
                                                           float* __restrict__ nll,
                                                           float* __restrict__ vld) {
  int r = blockIdx.x * 256 + threadIdx.x;
  float s = 0.f;
  for (int cb = 0; cb < NCB; ++cb) s += psum[(long)cb * M_ROWS + r];
  int tg = tgt[r];
  if (tg != -1) { nll[r] = logf(s) - logits[(size_t)r * V_SIZE + tg]; vld[r] = 1.0f; }
  else          { nll[r] = 0.f;                                       vld[r] = 0.f; }
}

__global__ __launch_bounds__(256) void loss_reduce_kernel(const float* __restrict__ nll,
                                                          const float* __restrict__ vld,
                                                          float* __restrict__ out) {
  int tid = threadIdx.x;
  float s = 0.f, c = 0.f;
  for (int i = tid; i < M_ROWS; i += 256) { s += nll[i]; c += vld[i]; }
  #pragma unroll
  for (int off = 32; off; off >>= 1) { s += __shfl_xor(s, off); c += __shfl_xor(c, off); }
  __shared__ float s1[4], s2[4];
  int w = tid >> 6, lane = tid & 63;
  if (lane == 0) { s1[w] = s; s2[w] = c; }
  __syncthreads();
  if (tid == 0) {
    s = s1[0] + s1[1] + s1[2] + s1[3];
    c = s2[0] + s2[1] + s2[2] + s2[3];
    out[0] = s / fmaxf(c, 1.0f);
  }
}

extern "C" void kernel_launch(void* const* d_in, const int* in_sizes, int n_in,
                              void* d_out, int out_size, void* d_ws, size_t ws_size,
                              hipStream_t stream) {
  const int*   ctx    = (const int*)d_in[0];
  const int*   tgt    = (const int*)d_in[1];
  const float* wte    = (const float*)d_in[2];
  const float* wpe    = (const float*)d_in[3];
  const float* ln1_g  = (const float*)d_in[4];
  const float* ln1_b  = (const float*)d_in[5];
  const float* w_attn = (const float*)d_in[6];
  const float* w_proj = (const float*)d_in[7];
  const float* ln2_g  = (const float*)d_in[8];
  const float* ln2_b  = (const float*)d_in[9];
  const float* w_fc   = (const float*)d_in[10];
  const float* w_out  = (const float*)d_in[11];
  const float* lnf_g  = (const float*)d_in[12];
  const float* lnf_b  = (const float*)d_in[13];

  float* outp   = (float*)d_out;
  float* logits = outp;
  float* loss   = outp + (size_t)M_ROWS * V_SIZE;

  // ---- workspace layout (bytes), max ~132 MB ----
  char* ws = (char*)d_ws;
  float*          x      = (float*)(ws + 0);                    // fp32 [4096][1024]
  unsigned short* xn     = (unsigned short*)(ws + 16777216);    // bf16 [4096][1024]
  unsigned short* qkv    = (unsigned short*)(ws + 25165824);    // bf16 [4096][3072]
  unsigned short* y      = (unsigned short*)(ws + 50331648);    // bf16 [4096][1024]
  unsigned short* h      = (unsigned short*)(ws + 58720256);    // bf16 [4096][4096]
  unsigned short* wa_bf  = (unsigned short*)(ws + 92274688);
  unsigned short* wp_bf  = (unsigned short*)(ws + 98566144);
  unsigned short* wf_bf  = (unsigned short*)(ws + 100663296);
  unsigned short* wo_bf  = (unsigned short*)(ws + 109051904);
  unsigned short* wte_bf = (unsigned short*)(ws + 25165824);    // alias post-loop [50432][1024]
  float*          nll    = (float*)(ws + 128450560);
  float*          vld    = (float*)(ws + 128466944);
  float*          psum   = (float*)(ws + 128483328);            // [197][4096] fp32

  embed_kernel<<<(M_ROWS * D_DIM + 255) / 256, 256, 0, stream>>>(ctx, wte, wpe, x);

  for (int l = 0; l < L_NUM; ++l) {
    conv_layer_kernel<<<6144, 256, 0, stream>>>(
        w_attn + (size_t)l * 3 * D_DIM * D_DIM, w_proj + (size_t)l * D_DIM * D_DIM,
        w_fc + (size_t)l * 4 * D_DIM * D_DIM, w_out + (size_t)l * D_DIM * 4 * D_DIM,
        wa_bf, wp_bf, wf_bf, wo_bf);
    layernorm_kernel<<<M_ROWS, 256, 0, stream>>>(x, ln1_g + l * D_DIM, ln1_b + l * D_DIM, xn);
    gemm8p<3><<<12 * 16, 512, 0, stream>>>(
        xn, wa_bf, qkv, D_DIM, 3 * D_DIM, 3 * D_DIM, 16, 1, nullptr);
    flash_attn_kernel<<<dim3(T_LEN / 128, B_NUM * H_NUM), 512, 0, stream>>>(qkv, y);
    mfma_gemm<1><<<dim3(D_DIM / 128, M_ROWS / 128), 256, 0, stream>>>(
        y, wp_bf, x, x, D_DIM, D_DIM, D_DIM);
    layernorm_kernel<<<M_ROWS, 256, 0, stream>>>(x, ln2_g + l * D_DIM, ln2_b + l * D_DIM, xn);
    gemm8p<2><<<16 * 16, 512, 0, stream>>>(
        xn, wf_bf, h, D_DIM, 4 * D_DIM, 4 * D_DIM, 16, 1, nullptr);
    mfma_gemm<1><<<dim3(D_DIM / 128, M_ROWS / 128), 256, 0, stream>>>(
        h, wo_bf, x, x, 4 * D_DIM, D_DIM, D_DIM);
  }

  layernorm_kernel<<<M_ROWS, 256, 0, stream>>>(x, lnf_g, lnf_b, xn);
  conv_kernel<<<25129, 256, 0, stream>>>(wte, wte_bf, (long)V_SIZE * D_DIM);
  hipMemsetAsync(wte_bf + (size_t)V_SIZE * D_DIM, 0,
                 (size_t)(V_PAD - V_SIZE) * D_DIM * sizeof(unsigned short), stream);
  gemm8p<0><<<NCB * 16, 512, 0, stream>>>(
      xn, wte_bf, logits, D_DIM, V_SIZE, V_SIZE, 16, 1, psum);
  loss_combine_kernel<<<M_ROWS / 256, 256, 0, stream>>>(psum, logits, tgt, nll, vld);
  loss_reduce_kernel<<<1, 256, 0, stream>>>(nll, vld, loss);
}

// Round 17
// 3004.582 us; speedup vs baseline: 1.0107x; 1.0107x over previous
//
#include <hip/hip_runtime.h>
#include <cstdint>

#define V_SIZE 50257
#define V_PAD  50432            // 197 * 256
#define NCB    197              // logits col-blocks
#define D_DIM  1024
#define H_NUM  16
#define L_NUM  8
#define T_LEN  1024
#define B_NUM  4
#define HD_DIM 64
#define M_ROWS 4096
#define LN_EPS 1e-5f

typedef __attribute__((ext_vector_type(8))) __bf16 bf16x8;
typedef __attribute__((ext_vector_type(4))) float f32x4;
typedef __attribute__((ext_vector_type(4))) float fv4;
typedef __attribute__((ext_vector_type(8))) unsigned short u16x8;

__device__ __forceinline__ unsigned short f2bf(float f) {
  unsigned u = __builtin_bit_cast(unsigned, f);
  u += 0x7fffu + ((u >> 16) & 1u);   // RNE
  return (unsigned short)(u >> 16);
}

__device__ __forceinline__ void gload_lds16(const void* g, void* l) {
  typedef const __attribute__((address_space(1))) unsigned int* gp_t;
  typedef __attribute__((address_space(3))) unsigned int* lp_t;
  __builtin_amdgcn_global_load_lds((gp_t)g, (lp_t)l, 16, 0, 0);
}

__device__ __forceinline__ f32x4 mfma16(bf16x8 a, bf16x8 b, f32x4 c) {
  return __builtin_amdgcn_mfma_f32_16x16x32_bf16(a, b, c, 0, 0, 0);
}

#define BARSB() { __builtin_amdgcn_s_barrier(); __builtin_amdgcn_sched_barrier(0); }
#define SCHB()  __builtin_amdgcn_sched_barrier(0)

// ---------------- embedding ----------------
__global__ __launch_bounds__(256) void embed_kernel(const int* __restrict__ ctx,
                                                    const float* __restrict__ wte,
                                                    const float* __restrict__ wpe,
                                                    float* __restrict__ x) {
  int i = blockIdx.x * blockDim.x + threadIdx.x;
  if (i >= M_ROWS * D_DIM) return;
  int bt = i / D_DIM, d = i - bt * D_DIM;
  int t = bt & (T_LEN - 1);
  x[i] = wte[(size_t)ctx[bt] * D_DIM + d] + wpe[(size_t)t * D_DIM + d];
}

// ---------------- fp32 -> bf16 weight conversion (NT source loads) ----------------
__global__ __launch_bounds__(256) void conv_layer_kernel(const float* __restrict__ wa,
                                                         const float* __restrict__ wp,
                                                         const float* __restrict__ wf,
                                                         const float* __restrict__ wo,
                                                         unsigned short* __restrict__ oa,
                                                         unsigned short* __restrict__ op,
                                                         unsigned short* __restrict__ of,
                                                         unsigned short* __restrict__ oo) {
  long i = (long)(blockIdx.x * 256 + threadIdx.x) * 8;
  const float* src; unsigned short* dst; long off;
  if (i < 3145728L)      { src = wa; dst = oa; off = i; }
  else if (i < 4194304L) { src = wp; dst = op; off = i - 3145728L; }
  else if (i < 8388608L) { src = wf; dst = of; off = i - 4194304L; }
  else                   { src = wo; dst = oo; off = i - 8388608L; }
  fv4 v0 = __builtin_nontemporal_load((const fv4*)(src + off));
  fv4 v1 = __builtin_nontemporal_load((const fv4*)(src + off + 4));
  u16x8 o;
  o[0] = f2bf(v0[0]); o[1] = f2bf(v0[1]); o[2] = f2bf(v0[2]); o[3] = f2bf(v0[3]);
  o[4] = f2bf(v1[0]); o[5] = f2bf(v1[1]); o[6] = f2bf(v1[2]); o[7] = f2bf(v1[3]);
  *(u16x8*)(dst + off) = o;
}

__global__ __launch_bounds__(256) void conv_kernel(const float* __restrict__ in,
                                                   unsigned short* __restrict__ out, long n) {
  long i = (long)(blockIdx.x * 256 + threadIdx.x) * 8;
  if (i >= n) return;
  fv4 v0 = __builtin_nontemporal_load((const fv4*)(in + i));
  fv4 v1 = __builtin_nontemporal_load((const fv4*)(in + i + 4));
  u16x8 o;
  o[0] = f2bf(v0[0]); o[1] = f2bf(v0[1]); o[2] = f2bf(v0[2]); o[3] = f2bf(v0[3]);
  o[4] = f2bf(v1[0]); o[5] = f2bf(v1[1]); o[6] = f2bf(v1[2]); o[7] = f2bf(v1[3]);
  *(u16x8*)(out + i) = o;
}

// ---------------- layernorm: one wave per row, 4 rows per block ----------------
// Lane holds 16 elems (4x float4, stride-256 coalesced); mean/var via one
// 6-level shfl pair; no LDS, no barriers. Grid = M/4 blocks.
__global__ __launch_bounds__(256) void layernorm_kernel(const float* __restrict__ x,
                                                        const float* __restrict__ g,
                                                        const float* __restrict__ b,
                                                        unsigned short* __restrict__ o) {
  const int wave = threadIdx.x >> 6, lane = threadIdx.x & 63;
  const long r = (long)blockIdx.x * 4 + wave;
  const float* row = x + r * D_DIM;
  fv4 v[4];
  float s = 0.f, s2 = 0.f;
  #pragma unroll
  for (int i = 0; i < 4; ++i) {
    v[i] = *(const fv4*)(row + i * 256 + lane * 4);
    #pragma unroll
    for (int j = 0; j < 4; ++j) { s += v[i][j]; s2 += v[i][j] * v[i][j]; }
  }
  #pragma unroll
  for (int off = 1; off < 64; off <<= 1) {
    s  += __shfl_xor(s, off);
    s2 += __shfl_xor(s2, off);
  }
  float mu  = s * (1.0f / D_DIM);
  float var = s2 * (1.0f / D_DIM) - mu * mu;
  float rs  = rsqrtf(var + LN_EPS);
  #pragma unroll
  for (int i = 0; i < 4; ++i) {
    int d = i * 256 + lane * 4;
    fv4 gv = *(const fv4*)(g + d);
    fv4 bv = *(const fv4*)(b + d);
    ushort4 ov;
    ov.x = f2bf((v[i][0] - mu) * rs * gv[0] + bv[0]);
    ov.y = f2bf((v[i][1] - mu) * rs * gv[1] + bv[1]);
    ov.z = f2bf((v[i][2] - mu) * rs * gv[2] + bv[2]);
    ov.w = f2bf((v[i][3] - mu) * rs * gv[3] + bv[3]);
    *(ushort4*)(o + r * D_DIM + d) = ov;
  }
}

// ---------------- m97-structure 128x128 bf16 MFMA GEMM (proj/out) ----------
template<int EPI>
__global__ __launch_bounds__(256) void mfma_gemm(const unsigned short* __restrict__ A,
                                                 const unsigned short* __restrict__ W,
                                                 const float* R, void* Cout,
                                                 int K, int ldc, int nreal) {
  __shared__ unsigned short As[128 * 32];
  __shared__ unsigned short Bs[128 * 32];
  const int tid  = threadIdx.x;
  const int wave = tid >> 6, lane = tid & 63;
  const int wr = wave >> 1, wc = wave & 1;
  const long row0 = (long)blockIdx.y * 128;
  const long col0 = (long)blockIdx.x * 128;
  f32x4 acc[4][4] = {};
  const int frow = lane & 15;
  const int fk   = (lane >> 4) * 8;
  const int b0 = wave * 2048 + lane * 16;
  for (int k0 = 0; k0 < K; k0 += 32) {
    #pragma unroll
    for (int c = 0; c < 2; ++c) {
      int b = b0 + c * 1024;
      int r = b >> 6, ke = (b & 63) >> 1;
      gload_lds16(A + (row0 + r) * (long)K + k0 + ke, (char*)As + b);
      gload_lds16(W + (col0 + r) * (long)K + k0 + ke, (char*)Bs + b);
    }
    __syncthreads();
    bf16x8 af[4], bfr[4];
    #pragma unroll
    for (int i = 0; i < 4; ++i)
      af[i] = *(const bf16x8*)(As + (wr * 64 + i * 16 + frow) * 32 + fk);
    #pragma unroll
    for (int j = 0; j < 4; ++j)
      bfr[j] = *(const bf16x8*)(Bs + (wc * 64 + j * 16 + frow) * 32 + fk);
    #pragma unroll
    for (int i = 0; i < 4; ++i)
      #pragma unroll
      for (int j = 0; j < 4; ++j)
        acc[i][j] = mfma16(af[i], bfr[j], acc[i][j]);
    __syncthreads();
  }
  const int crow = (lane >> 4) * 4;
  const int ccol = lane & 15;
  #pragma unroll
  for (int i = 0; i < 4; ++i) {
    #pragma unroll
    for (int r = 0; r < 4; ++r) {
      long row = row0 + wr * 64 + i * 16 + crow + r;
      #pragma unroll
      for (int j = 0; j < 4; ++j) {
        long col = col0 + wc * 64 + j * 16 + ccol;
        float v = acc[i][j][r];
        if (EPI == 1) {
          ((float*)Cout)[row * (long)ldc + col] = v + R[row * (long)ldc + col];
        } else {
          ((float*)Cout)[row * (long)ldc + col] = v;
        }
      }
    }
  }
}

// ---------------- 256x256 software-pipelined bf16 GEMM, 16x16x32 MFMA ----------
__device__ __forceinline__ void stage_chunk8(const unsigned short* __restrict__ base,
                                             long rbase, int K, long gk,
                                             char* cb, int tid) {
  #pragma unroll
  for (int j = 0; j < 2; ++j) {
    int db = j * 8192 + tid * 16;
    int lb = db ^ (((db >> 7) & 3) << 4);
    long r = lb >> 6;
    int e = (lb & 63) >> 1;
    gload_lds16(base + (rbase + r) * (long)K + gk + e, cb + db);
  }
}

__device__ __forceinline__ bf16x8 rdfrag(const char* cb, int rr, int lhi) {
  int p = (rr << 6) + (lhi << 4);
  p ^= ((rr >> 1) & 3) << 4;
  return *(const bf16x8*)(cb + p);
}

template<int EPI>
__global__ __launch_bounds__(512, 1) void gemm8p(const unsigned short* __restrict__ A,
                                                 const unsigned short* __restrict__ W,
                                                 void* Cout, int K, int ldc, int nreal,
                                                 int nbx, int xcd,
                                                 float* __restrict__ psum) {
  __shared__ char lds[131072];
  const int tid  = threadIdx.x;
  const int lane = tid & 63;
  const int wave = tid >> 6;
  const int wr = wave >> 2, wc = wave & 3;
  const int lhi = lane >> 4, llo = lane & 15;
  int bid = blockIdx.x;
  if (xcd) { int per = (int)gridDim.x >> 3; bid = (bid & 7) * per + (bid >> 3); }
  const int brow = bid % nbx;
  const int bcol = bid / nbx;
  const long row0 = (long)brow * 256;
  const long col0 = (long)bcol * 256;
  char* Ab0 = (char*)lds;
  char* Bb0 = (char*)lds + 65536;
  const int nt = K >> 6;   // nt >= 3 assumed (all uses: nt = 16)

  stage_chunk8(W, col0, K, 0,  Bb0,         tid);
  stage_chunk8(A, row0, K, 0,  Ab0,         tid);
  stage_chunk8(W, col0, K, 32, Bb0 + 16384, tid);
  stage_chunk8(A, row0, K, 32, Ab0 + 16384, tid);
  stage_chunk8(W, col0, K, 64, Bb0 + 32768, tid);
  stage_chunk8(A, row0, K, 64, Ab0 + 32768, tid);
  stage_chunk8(W, col0, K, 96, Bb0 + 49152, tid);
  asm volatile("s_waitcnt vmcnt(10)" ::: "memory");
  BARSB();

  const int arow  = wr * 128 + llo;
  const int brow_ = wc * 64 + llo;

  bf16x8 aa0[4], aa1[4], bb0[4], bb1[4];
  #pragma unroll
  for (int m = 0; m < 4; ++m) aa0[m] = rdfrag(Ab0, arow + m * 16, lhi);
  #pragma unroll
  for (int n = 0; n < 4; ++n) bb0[n] = rdfrag(Bb0, brow_ + n * 16, lhi);

  f32x4 acc[8][4] = {};
  for (int t = 0; t < nt; ++t) {
    char* Ac = Ab0 + (t & 1) * 32768;
    char* Bc = Bb0 + (t & 1) * 32768;
    char* An = Ab0 + ((t + 1) & 1) * 32768;
    char* Bn = Bb0 + ((t + 1) & 1) * 32768;
    // ===== S0
    #pragma unroll
    for (int m = 0; m < 4; ++m) aa1[m] = rdfrag(Ac, arow + 64 + m * 16, lhi);
    asm volatile("s_waitcnt lgkmcnt(4)" ::: "memory");
    SCHB();
    if (t + 1 < nt) stage_chunk8(A, row0, K, (long)(t + 1) * 64 + 32, An + 16384, tid);
    __builtin_amdgcn_s_setprio(1);
    #pragma unroll
    for (int m = 0; m < 4; ++m)
      #pragma unroll
      for (int n = 0; n < 4; ++n)
        acc[m][n] = mfma16(aa0[m], bb0[n], acc[m][n]);
    __builtin_amdgcn_s_setprio(0);
    SCHB();
    if (t < nt - 1) { asm volatile("s_waitcnt vmcnt(8)" ::: "memory"); }
    else            { asm volatile("s_waitcnt vmcnt(0)" ::: "memory"); }
    BARSB();
    // ===== S1
    #pragma unroll
    for (int m = 0; m < 4; ++m) aa0[m] = rdfrag(Ac + 16384, arow + m * 16, lhi);
    #pragma unroll
    for (int n = 0; n < 4; ++n) bb1[n] = rdfrag(Bc + 16384, brow_ + n * 16, lhi);
    asm volatile("s_waitcnt lgkmcnt(8)" ::: "memory");
    SCHB();
    if (t + 2 < nt) stage_chunk8(W, col0, K, (long)(t + 2) * 64, Bc, tid);
    __builtin_amdgcn_s_setprio(1);
    #pragma unroll
    for (int m = 0; m < 4; ++m)
      #pragma unroll
      for (int n = 0; n < 4; ++n)
        acc[m + 4][n] = mfma16(aa1[m], bb0[n], acc[m + 4][n]);
    __builtin_amdgcn_s_setprio(0);
    SCHB();
    BARSB();
    // ===== S2
    #pragma unroll
    for (int m = 0; m < 4; ++m) aa1[m] = rdfrag(Ac + 16384, arow + 64 + m * 16, lhi);
    asm volatile("s_waitcnt lgkmcnt(4)" ::: "memory");
    SCHB();
    if (t + 2 < nt) stage_chunk8(A, row0, K, (long)(t + 2) * 64, Ac, tid);
    __builtin_amdgcn_s_setprio(1);
    #pragma unroll
    for (int m = 0; m < 4; ++m)
      #pragma unroll
      for (int n = 0; n < 4; ++n)
        acc[m][n] = mfma16(aa0[m], bb1[n], acc[m][n]);
    __builtin_amdgcn_s_setprio(0);
    SCHB();
    if (t <= nt - 3)      { asm volatile("s_waitcnt vmcnt(8)" ::: "memory"); }
    else if (t == nt - 2) { asm volatile("s_waitcnt vmcnt(4)" ::: "memory"); }
    else                  { asm volatile("s_waitcnt vmcnt(0)" ::: "memory"); }
    BARSB();
    // ===== S3
    if (t + 1 < nt) {
      #pragma unroll
      for (int m = 0; m < 4; ++m) aa0[m] = rdfrag(An, arow + m * 16, lhi);
      #pragma unroll
      for (int n = 0; n < 4; ++n) bb0[n] = rdfrag(Bn, brow_ + n * 16, lhi);
      asm volatile("s_waitcnt lgkmcnt(8)" ::: "memory");
    } else {
      asm volatile("s_waitcnt lgkmcnt(0)" ::: "memory");
    }
    SCHB();
    if (t + 2 < nt) stage_chunk8(W, col0, K, (long)(t + 2) * 64 + 32, Bc + 16384, tid);
    __builtin_amdgcn_s_setprio(1);
    #pragma unroll
    for (int m = 0; m < 4; ++m)
      #pragma unroll
      for (int n = 0; n < 4; ++n)
        acc[m + 4][n] = mfma16(aa1[m], bb1[n], acc[m + 4][n]);
    __builtin_amdgcn_s_setprio(0);
    SCHB();
    BARSB();
  }

  // ---- epilogue: stores (C/D 16x16 layout: col=lane&15, row=(lane>>4)*4+reg)
  #pragma unroll
  for (int mi = 0; mi < 8; ++mi) {
    #pragma unroll
    for (int rg = 0; rg < 4; ++rg) {
      long row = row0 + wr * 128 + mi * 16 + lhi * 4 + rg;
      #pragma unroll
      for (int n = 0; n < 4; ++n) {
        long col = col0 + wc * 64 + n * 16 + llo;
        float v = acc[mi][n][rg];
        if (EPI == 0) {
          if (col < nreal) ((float*)Cout)[row * (long)ldc + col] = v;
        } else if (EPI == 2) {
          float gl = 0.5f * v * (1.0f + erff(v * 0.70710678118654752440f));
          ((unsigned short*)Cout)[row * (long)ldc + col] = f2bf(gl);
        } else {
          ((unsigned short*)Cout)[row * (long)ldc + col] = f2bf(v);
        }
      }
    }
  }

  if (EPI == 0) {
    // exp-direct LSE partials (logits are small; no max tracking needed)
    float* red = (float*)lds;   // [256 rows][4 wc]
    #pragma unroll
    for (int mi = 0; mi < 8; ++mi) {
      #pragma unroll
      for (int rg = 0; rg < 4; ++rg) {
        float e = 0.f;
        #pragma unroll
        for (int n = 0; n < 4; ++n) {
          long col = col0 + wc * 64 + n * 16 + llo;
          if (col < nreal) e += __expf(acc[mi][n][rg]);
        }
        #pragma unroll
        for (int off = 1; off < 16; off <<= 1) e += __shfl_xor(e, off);
        if (llo == 0) {
          int rl = wr * 128 + mi * 16 + lhi * 4 + rg;
          red[rl * 4 + wc] = e;
        }
      }
    }
    __syncthreads();
    if (tid < 256) {
      float s = red[tid * 4 + 0] + red[tid * 4 + 1] + red[tid * 4 + 2] + red[tid * 4 + 3];
      psum[(long)bcol * M_ROWS + row0 + tid] = s;
    }
  }
}

// ---------------- MFMA flash attention: 128-query blocks, swapped QK^T softmax ------
// (round-15 version: single-buffer K/V, 4 blocks/CU)
__global__ __launch_bounds__(512) void flash_attn_kernel(const unsigned short* __restrict__ qkv,
                                                         unsigned short* __restrict__ y) {
  __shared__ unsigned short Kls[64 * 64];
  __shared__ unsigned short Vtls[64 * 64];
  __shared__ unsigned short Pls[8][16 * 64];
  const int tid = threadIdx.x, wave = tid >> 6, lane = tid & 63;
  const int qt = blockIdx.x;                     // 0..7
  const int h = blockIdx.y & (H_NUM - 1), b = blockIdx.y >> 4;
  const int q0 = qt * 128;
  const int lhi = lane >> 4, llo = lane & 15;

  const int qrow = q0 + wave * 16 + llo;
  const unsigned short* qptr =
      qkv + ((size_t)(b * T_LEN + qrow)) * 3072 + h * HD_DIM + lhi * 8;
  const bf16x8 qa0 = *(const bf16x8*)qptr;
  const bf16x8 qa1 = *(const bf16x8*)(qptr + 32);

  f32x4 o[4] = {};
  float m = -1e30f, l = 0.f;      // per-lane running stats for q = llo

  const unsigned short* kg = qkv + (size_t)b * T_LEN * 3072 + D_DIM + h * HD_DIM;
  const unsigned short* vg = kg + D_DIM;

  const int vs0 = ((tid & 255) >> 3) * 2, vd0 = (tid & 7) * 8;   // tid<256: V
  const int t2 = tid - 256;
  const int krow = (t2 & 255) >> 2, kcol = (t2 & 3) * 16;        // tid>=256: K

  const int ntiles = 2 * qt + 2;

  // preload tile 0 into registers
  u16x8 ra, rc;
  if (tid < 256) {
    const unsigned short* src = vg + (size_t)vs0 * 3072 + vd0;
    ra = *(const u16x8*)src;
    rc = *(const u16x8*)(src + 3072);
  } else {
    const unsigned short* src = kg + (size_t)krow * 3072 + kcol;
    ra = *(const u16x8*)src;
    rc = *(const u16x8*)(src + 8);
  }

  for (int st = 0; st < ntiles; ++st) {
    // ---- write staged regs -> LDS (swizzled) ----
    if (tid < 256) {
      #pragma unroll
      for (int j = 0; j < 8; ++j) {
        int d = vd0 + j;
        unsigned val = (unsigned)ra[j] | ((unsigned)rc[j] << 16);
        *(unsigned*)((char*)Vtls + ((d * 128 + vs0 * 2) ^ ((d & 7) << 4))) = val;
      }
    } else {
      int base = krow * 128 + kcol * 2;
      int sw = (krow & 7) << 4;
      *(u16x8*)((char*)Kls + ((base) ^ sw))      = ra;
      *(u16x8*)((char*)Kls + ((base + 16) ^ sw)) = rc;
    }
    __syncthreads();
    // ---- issue next tile's global loads (latency hidden by compute below) ----
    if (st + 1 < ntiles) {
      const int s1 = (st + 1) * 64;
      if (tid < 256) {
        const unsigned short* src = vg + (size_t)(s1 + vs0) * 3072 + vd0;
        ra = *(const u16x8*)src;
        rc = *(const u16x8*)(src + 3072);
      } else {
        const unsigned short* src = kg + (size_t)(s1 + krow) * 3072 + kcol;
        ra = *(const u16x8*)src;
        rc = *(const u16x8*)(src + 8);
      }
    }

    const int s0 = st * 64;
    // ---- swapped QK^T: D = K_tile(A) x Q(B) -> S^T[key][q], col=q=llo ----
    f32x4 t_acc[4] = {};
    #pragma unroll
    for (int kt = 0; kt < 4; ++kt) {
      int kr = kt * 16 + llo;
      int sw = (kr & 7) << 4;
      bf16x8 kb0 = *(const bf16x8*)((char*)Kls + ((kr * 128 + lhi * 16) ^ sw));
      bf16x8 kb1 = *(const bf16x8*)((char*)Kls + ((kr * 128 + 64 + lhi * 16) ^ sw));
      t_acc[kt] = mfma16(kb0, qa0, t_acc[kt]);
      t_acc[kt] = mfma16(kb1, qa1, t_acc[kt]);
    }

    // ---- softmax: lane owns q = q0+wave*16+llo; 16 scores in registers ----
    const int qg = q0 + wave * 16 + llo;
    float p[4][4];
    float tmax = -1e30f;
    #pragma unroll
    for (int kt = 0; kt < 4; ++kt) {
      #pragma unroll
      for (int rg = 0; rg < 4; ++rg) {
        int key = s0 + kt * 16 + lhi * 4 + rg;
        float sv = (key <= qg) ? t_acc[kt][rg] * 0.125f : -1e30f;
        p[kt][rg] = sv;
        tmax = fmaxf(tmax, sv);
      }
    }
    tmax = fmaxf(tmax, __shfl_xor(tmax, 16));
    tmax = fmaxf(tmax, __shfl_xor(tmax, 32));
    float mn = fmaxf(m, tmax);
    float corr = __expf(m - mn);
    m = mn;
    float ps = 0.f;
    #pragma unroll
    for (int kt = 0; kt < 4; ++kt) {
      #pragma unroll
      for (int rg = 0; rg < 4; ++rg) {
        p[kt][rg] = __expf(p[kt][rg] - mn);
        ps += p[kt][rg];
      }
    }
    ps += __shfl_xor(ps, 16);
    ps += __shfl_xor(ps, 32);
    l = l * corr + ps;
    // redistribute corr to o's rows (q' = lhi*4 + r held by lane llo=q')
    float corr4[4];
    #pragma unroll
    for (int r = 0; r < 4; ++r) corr4[r] = __shfl(corr, lhi * 4 + r);
    #pragma unroll
    for (int dt = 0; dt < 4; ++dt)
      #pragma unroll
      for (int r = 0; r < 4; ++r) o[dt][r] *= corr4[r];

    // ---- write P (bf16) to wave-private LDS [q=llo][k], swizzled ----
    unsigned short* pw = Pls[wave];
    {
      int sw = (llo & 7) << 4;
      #pragma unroll
      for (int kt = 0; kt < 4; ++kt) {
        #pragma unroll
        for (int rg = 0; rg < 4; ++rg) {
          int k = kt * 16 + lhi * 4 + rg;
          *(unsigned short*)((char*)pw + ((llo * 128 + k * 2) ^ sw)) = f2bf(p[kt][rg]);
        }
      }
    }
    asm volatile("s_waitcnt lgkmcnt(0)" ::: "memory");

    int psw = (llo & 7) << 4;
    bf16x8 pa0 = *(const bf16x8*)((char*)pw + ((llo * 128 + lhi * 16) ^ psw));
    bf16x8 pa1 = *(const bf16x8*)((char*)pw + ((llo * 128 + 64 + lhi * 16) ^ psw));
    #pragma unroll
    for (int dt = 0; dt < 4; ++dt) {
      int vr = dt * 16 + llo;
      int sw = (vr & 7) << 4;
      bf16x8 vb0 = *(const bf16x8*)((char*)Vtls + ((vr * 128 + lhi * 16) ^ sw));
      bf16x8 vb1 = *(const bf16x8*)((char*)Vtls + ((vr * 128 + 64 + lhi * 16) ^ sw));
      o[dt] = mfma16(pa0, vb0, o[dt]);
      o[dt] = mfma16(pa1, vb1, o[dt]);
    }
    __syncthreads();
  }

  // ---- epilogue: l for o's rows fetched from lane llo = lhi*4+r ----
  #pragma unroll
  for (int r = 0; r < 4; ++r) {
    float lr = __shfl(l, lhi * 4 + r);
    float inv = 1.0f / lr;
    long row = q0 + wave * 16 + lhi * 4 + r;
    #pragma unroll
    for (int dt = 0; dt < 4; ++dt) {
      long col = h * HD_DIM + dt * 16 + llo;
      y[(row + (size_t)b * T_LEN) * D_DIM + col] = f2bf(o[dt][r] * inv);
    }
  }
}

// ---------------- loss: sum per-colblock exp-partials ----------------
__global__ __launch_bounds__(256) void loss_combine_kernel(const float* __restrict__ psum,
                                                           const float* __restrict__ logits,
                                                           const int* __restrict__ tgt,
                                                           float* __restrict__ nll,
                                                           float* __restrict__ vld) {
  int r = blockIdx.x * 256 + threadIdx.x;
  float s = 0.f;
  for (int cb = 0; cb < NCB; ++cb) s += psum[(long)cb * M_ROWS + r];
  int tg = tgt[r];
  if (tg != -1) { nll[r] = logf(s) - logits[(size_t)r * V_SIZE + tg]; vld[r] = 1.0f; }
  else          { nll[r] = 0.f;                                       vld[r] = 0.f; }
}

__global__ __launch_bounds__(256) void loss_reduce_kernel(const float* __restrict__ nll,
                                                          const float* __restrict__ vld,
                                                          float* __restrict__ out) {
  int tid = threadIdx.x;
  float s = 0.f, c = 0.f;
  for (int i = tid; i < M_ROWS; i += 256) { s += nll[i]; c += vld[i]; }
  #pragma unroll
  for (int off = 32; off; off >>= 1) { s += __shfl_xor(s, off); c += __shfl_xor(c, off); }
  __shared__ float s1[4], s2[4];
  int w = tid >> 6, lane = tid & 63;
  if (lane == 0) { s1[w] = s; s2[w] = c; }
  __syncthreads();
  if (tid == 0) {
    s = s1[0] + s1[1] + s1[2] + s1[3];
    c = s2[0] + s2[1] + s2[2] + s2[3];
    out[0] = s / fmaxf(c, 1.0f);
  }
}

extern "C" void kernel_launch(void* const* d_in, const int* in_sizes, int n_in,
                              void* d_out, int out_size, void* d_ws, size_t ws_size,
                              hipStream_t stream) {
  const int*   ctx    = (const int*)d_in[0];
  const int*   tgt    = (const int*)d_in[1];
  const float* wte    = (const float*)d_in[2];
  const float* wpe    = (const float*)d_in[3];
  const float* ln1_g  = (const float*)d_in[4];
  const float* ln1_b  = (const float*)d_in[5];
  const float* w_attn = (const float*)d_in[6];
  const float* w_proj = (const float*)d_in[7];
  const float* ln2_g  = (const float*)d_in[8];
  const float* ln2_b  = (const float*)d_in[9];
  const float* w_fc   = (const float*)d_in[10];
  const float* w_out  = (const float*)d_in[11];
  const float* lnf_g  = (const float*)d_in[12];
  const float* lnf_b  = (const float*)d_in[13];

  float* outp   = (float*)d_out;
  float* logits = outp;
  float* loss   = outp + (size_t)M_ROWS * V_SIZE;

  // ---- workspace layout (bytes), max ~132 MB ----
  char* ws = (char*)d_ws;
  float*          x      = (float*)(ws + 0);                    // fp32 [4096][1024]
  unsigned short* xn     = (unsigned short*)(ws + 16777216);    // bf16 [4096][1024]
  unsigned short* qkv    = (unsigned short*)(ws + 25165824);    // bf16 [4096][3072]
  unsigned short* y      = (unsigned short*)(ws + 50331648);    // bf16 [4096][1024]
  unsigned short* h      = (unsigned short*)(ws + 58720256);    // bf16 [4096][4096]
  unsigned short* wa_bf  = (unsigned short*)(ws + 92274688);
  unsigned short* wp_bf  = (unsigned short*)(ws + 98566144);
  unsigned short* wf_bf  = (unsigned short*)(ws + 100663296);
  unsigned short* wo_bf  = (unsigned short*)(ws + 109051904);
  unsigned short* wte_bf = (unsigned short*)(ws + 25165824);    // alias post-loop [50432][1024]
  float*          nll    = (float*)(ws + 128450560);
  float*          vld    = (float*)(ws + 128466944);
  float*          psum   = (float*)(ws + 128483328);            // [197][4096] fp32

  embed_kernel<<<(M_ROWS * D_DIM + 255) / 256, 256, 0, stream>>>(ctx, wte, wpe, x);

  for (int l = 0; l < L_NUM; ++l) {
    conv_layer_kernel<<<6144, 256, 0, stream>>>(
        w_attn + (size_t)l * 3 * D_DIM * D_DIM, w_proj + (size_t)l * D_DIM * D_DIM,
        w_fc + (size_t)l * 4 * D_DIM * D_DIM, w_out + (size_t)l * D_DIM * 4 * D_DIM,
        wa_bf, wp_bf, wf_bf, wo_bf);
    layernorm_kernel<<<M_ROWS / 4, 256, 0, stream>>>(x, ln1_g + l * D_DIM, ln1_b + l * D_DIM, xn);
    gemm8p<3><<<12 * 16, 512, 0, stream>>>(
        xn, wa_bf, qkv, D_DIM, 3 * D_DIM, 3 * D_DIM, 16, 1, nullptr);
    flash_attn_kernel<<<dim3(T_LEN / 128, B_NUM * H_NUM), 512, 0, stream>>>(qkv, y);
    mfma_gemm<1><<<dim3(D_DIM / 128, M_ROWS / 128), 256, 0, stream>>>(
        y, wp_bf, x, x, D_DIM, D_DIM, D_DIM);
    layernorm_kernel<<<M_ROWS / 4, 256, 0, stream>>>(x, ln2_g + l * D_DIM, ln2_b + l * D_DIM, xn);
    gemm8p<2><<<16 * 16, 512, 0, stream>>>(
        xn, wf_bf, h, D_DIM, 4 * D_DIM, 4 * D_DIM, 16, 1, nullptr);
    mfma_gemm<1><<<dim3(D_DIM / 128, M_ROWS / 128), 256, 0, stream>>>(
        h, wo_bf, x, x, 4 * D_DIM, D_DIM, D_DIM);
  }

  layernorm_kernel<<<M_ROWS / 4, 256, 0, stream>>>(x, lnf_g, lnf_b, xn);
  conv_kernel<<<25129, 256, 0, stream>>>(wte, wte_bf, (long)V_SIZE * D_DIM);
  hipMemsetAsync(wte_bf + (size_t)V_SIZE * D_DIM, 0,
                 (size_t)(V_PAD - V_SIZE) * D_DIM * sizeof(unsigned short), stream);
  gemm8p<0><<<NCB * 16, 512, 0, stream>>>(
      xn, wte_bf, logits, D_DIM, V_SIZE, V_SIZE, 16, 1, psum);
  loss_combine_kernel<<<M_ROWS / 256, 256, 0, stream>>>(psum, logits, tgt, nll, vld);
  loss_reduce_kernel<<<1, 256, 0, stream>>>(nll, vld, loss);
}